// Round 1
// baseline (266.305 us; speedup 1.0000x reference)
//
#include <hip/hip_runtime.h>
#include <hip/hip_bf16.h>

#define NB 16
#define CCH 64
#define LL 4096   // 64*64
#define DD 1024   // 32*32

// ---------------------------------------------------------------------------
// Kernel 1: per-pixel 1x1 convs (theta, phi_pre, g_pre) + 2x2 maxpool of
// phi/g. Block = 256 threads = 4 rows x 64 cols of one batch image.
// theta stored [N, L, 8] (query-major), phi [N, D, 8], g [N, D, 32].
// ---------------------------------------------------------------------------
__global__ __launch_bounds__(256) void prep_kernel(
    const float* __restrict__ x,        // [N, 64, 4096]
    const float* __restrict__ w_theta,  // [8, 64]
    const float* __restrict__ w_phi,    // [8, 64]
    const float* __restrict__ w_g,      // [32, 64]
    float* __restrict__ theta_out,      // [N, 4096, 8]
    float* __restrict__ phi_out,        // [N, 1024, 8]
    float* __restrict__ g_out)          // [N, 1024, 32]
{
    __shared__ float pool[256][40];     // 40 KB: phi_pre[8] + g_pre[32] per pixel

    const int n   = blockIdx.x >> 4;    // 16 row-groups per batch image
    const int hg  = blockIdx.x & 15;    // rows h = hg*4 .. hg*4+3
    const int tid = threadIdx.x;
    const int lh  = tid >> 6;           // 0..3 local row
    const int lw  = tid & 63;           // 0..63 col
    const int l   = (hg * 4 + lh) * 64 + lw;

    const float* xp = x + (size_t)n * CCH * LL + l;

    // load the 64-channel pixel into registers (coalesced per channel)
    float xv[64];
#pragma unroll
    for (int c = 0; c < 64; ++c) xv[c] = xp[(size_t)c * LL];

    float th[8], ph[8], gg[32];
#pragma unroll
    for (int k = 0; k < 8; ++k) {
        float a = 0.f;
        const float* w = w_theta + k * 64;
#pragma unroll
        for (int c = 0; c < 64; ++c) a += w[c] * xv[c];
        th[k] = a;
    }
#pragma unroll
    for (int k = 0; k < 8; ++k) {
        float a = 0.f;
        const float* w = w_phi + k * 64;
#pragma unroll
        for (int c = 0; c < 64; ++c) a += w[c] * xv[c];
        ph[k] = a;
    }
#pragma unroll
    for (int j = 0; j < 32; ++j) {
        float a = 0.f;
        const float* w = w_g + j * 64;
#pragma unroll
        for (int c = 0; c < 64; ++c) a += w[c] * xv[c];
        gg[j] = a;
    }

    // theta out: 8 contiguous floats per query -> two float4 stores, coalesced
    float* tout = theta_out + ((size_t)n * LL + l) * 8;
    ((float4*)tout)[0] = make_float4(th[0], th[1], th[2], th[3]);
    ((float4*)tout)[1] = make_float4(th[4], th[5], th[6], th[7]);

    // stage phi_pre/g_pre for pooling
#pragma unroll
    for (int k = 0; k < 8; ++k) pool[tid][k] = ph[k];
#pragma unroll
    for (int j = 0; j < 32; ++j) pool[tid][8 + j] = gg[j];
    __syncthreads();

    // 2x2 maxpool: 64 pooled outputs (2 rows x 32 cols) x 40 values
    for (int idx = tid; idx < 64 * 40; idx += 256) {
        int q  = idx / 40;
        int f  = idx - q * 40;
        int qh = q >> 5, qw = q & 31;
        int p0 = (qh * 2) * 64 + qw * 2;
        float v = fmaxf(fmaxf(pool[p0][f], pool[p0 + 1][f]),
                        fmaxf(pool[p0 + 64][f], pool[p0 + 65][f]));
        int dd = (hg * 2 + qh) * 32 + qw;
        if (f < 8) phi_out[((size_t)n * DD + dd) * 8 + f] = v;
        else       g_out[((size_t)n * DD + dd) * 32 + (f - 8)] = v;
    }
}

// ---------------------------------------------------------------------------
// Kernel 2: fused flash-style attention. One query per thread.
// Block = 256 threads = 256 queries of one batch. phi fully in LDS (32 KB),
// g streamed in 4 chunks of 256 d (32 KB). acc[32] + running sum in regs
// (no max-subtraction: scores are O(1), exp is safe in fp32).
// ---------------------------------------------------------------------------
__global__ __launch_bounds__(256) void attn_kernel(
    const float* __restrict__ x,        // [N, 64, 4096]
    const float* __restrict__ theta,    // [N, 4096, 8]
    const float* __restrict__ phi,      // [N, 1024, 8]
    const float* __restrict__ g,        // [N, 1024, 32]
    const float* __restrict__ w_o,      // [64, 32]
    const float* __restrict__ gamma_p,  // scalar
    float* __restrict__ out)            // [N, 64, 4096]
{
    __shared__ float phi_s[DD * 8];     // 32 KB
    __shared__ float g_s[256 * 32];     // 32 KB

    const int n    = blockIdx.x >> 4;
    const int lblk = blockIdx.x & 15;
    const int tid  = threadIdx.x;
    const int l    = lblk * 256 + tid;

    // stage full phi[n] into LDS (coalesced float4)
    {
        const float4* src = (const float4*)(phi + (size_t)n * DD * 8);
        float4* dst = (float4*)phi_s;
        for (int i = tid; i < DD * 8 / 4; i += 256) dst[i] = src[i];
    }

    // per-query theta fragment
    const float4* tsrc = (const float4*)(theta + ((size_t)n * LL + l) * 8);
    float4 t0 = tsrc[0], t1 = tsrc[1];

    float acc[32];
#pragma unroll
    for (int j = 0; j < 32; ++j) acc[j] = 0.f;
    float ssum = 0.f;

    for (int ch = 0; ch < 4; ++ch) {
        __syncthreads();
        // stage g chunk [256][32] (coalesced float4)
        {
            const float4* src = (const float4*)(g + ((size_t)n * DD + ch * 256) * 32);
            float4* dst = (float4*)g_s;
            for (int i = tid; i < 256 * 32 / 4; i += 256) dst[i] = src[i];
        }
        __syncthreads();

#pragma unroll 2
        for (int d = 0; d < 256; ++d) {
            const int gd = ch * 256 + d;
            float4 pa = *(const float4*)(phi_s + gd * 8);
            float4 pb = *(const float4*)(phi_s + gd * 8 + 4);
            float s = t0.x * pa.x + t0.y * pa.y + t0.z * pa.z + t0.w * pa.w
                    + t1.x * pb.x + t1.y * pb.y + t1.z * pb.z + t1.w * pb.w;
            float e = __expf(s);
            ssum += e;
            const float4* gp4 = (const float4*)(g_s + d * 32);
#pragma unroll
            for (int j = 0; j < 8; ++j) {
                float4 gv = gp4[j];
                acc[4 * j + 0] += e * gv.x;
                acc[4 * j + 1] += e * gv.y;
                acc[4 * j + 2] += e * gv.z;
                acc[4 * j + 3] += e * gv.w;
            }
        }
    }

    const float inv = 1.0f / ssum;
#pragma unroll
    for (int j = 0; j < 32; ++j) acc[j] *= inv;

    const float gamma = gamma_p[0];
    const float* xp = x + (size_t)n * CCH * LL + l;
    float* op = out + (size_t)n * CCH * LL + l;

#pragma unroll 8
    for (int o = 0; o < 64; ++o) {
        const float* wrow = w_o + o * 32;   // wave-uniform -> s_load path
        float v = 0.f;
#pragma unroll
        for (int j = 0; j < 32; ++j) v += wrow[j] * acc[j];
        op[(size_t)o * LL] = xp[(size_t)o * LL] + gamma * v;
    }
}

// ---------------------------------------------------------------------------
extern "C" void kernel_launch(void* const* d_in, const int* in_sizes, int n_in,
                              void* d_out, int out_size, void* d_ws, size_t ws_size,
                              hipStream_t stream) {
    const float* x       = (const float*)d_in[0];
    const float* w_theta = (const float*)d_in[1];
    const float* w_phi   = (const float*)d_in[2];
    const float* w_g     = (const float*)d_in[3];
    const float* w_o     = (const float*)d_in[4];
    const float* gamma   = (const float*)d_in[5];
    float* out = (float*)d_out;

    // workspace layout (floats): theta 2 MB | phi 512 KB | g 2 MB
    float* theta_ws = (float*)d_ws;                       // N*L*8  = 524288
    float* phi_ws   = theta_ws + (size_t)NB * LL * 8;     // N*D*8  = 131072
    float* g_ws     = phi_ws   + (size_t)NB * DD * 8;     // N*D*32 = 524288

    prep_kernel<<<256, 256, 0, stream>>>(x, w_theta, w_phi, w_g,
                                         theta_ws, phi_ws, g_ws);
    attn_kernel<<<256, 256, 0, stream>>>(x, theta_ws, phi_ws, g_ws,
                                         w_o, gamma, out);
}

// Round 2
// 211.381 us; speedup vs baseline: 1.2598x; 1.2598x over previous
//
#include <hip/hip_runtime.h>
#include <hip/hip_bf16.h>

#define NB 16
#define CCH 64
#define LL 4096   // 64*64
#define DD 1024   // 32*32

// ---------------------------------------------------------------------------
// Kernel 1: 1x1 convs (theta, phi_pre, g_pre) + 2x2 maxpool, 4-way channel
// split for occupancy. Block = 256 thr = 64 pixels (2 rows x 32 cols) x 4
// channel-quarters. Grid = N * 32 rowpairs * 2 colhalves = 1024 blocks.
// Partial reduction through LDS with stride 193 (==1 mod 32, conflict-free).
// ---------------------------------------------------------------------------
__global__ __launch_bounds__(256) void prep_kernel(
    const float* __restrict__ x,        // [N, 64, 4096]
    const float* __restrict__ w_theta,  // [8, 64]
    const float* __restrict__ w_phi,    // [8, 64]
    const float* __restrict__ w_g,      // [32, 64]
    float* __restrict__ theta_out,      // [N, 4096, 8]
    float* __restrict__ phi_out,        // [N, 1024, 8]
    float* __restrict__ g_out)          // [N, 1024, 32]
{
    __shared__ float part[64][193];     // 49.4 KB -> 3 blocks/CU, 12 waves/CU

    const int n    = blockIdx.x >> 6;
    const int rem  = blockIdx.x & 63;
    const int rg   = rem >> 1;          // row-pair 0..31 (rows 2rg, 2rg+1)
    const int half = rem & 1;           // column half (32 cols each)
    const int tid  = threadIdx.x;
    const int cs   = tid >> 6;          // channel quarter 0..3 (one per wave)
    const int pix  = tid & 63;          // row = pix>>5, col = pix&31
    const int row  = pix >> 5;
    const int col  = pix & 31;
    const int l    = (rg * 2 + row) * 64 + half * 32 + col;

    const float* xp = x + (size_t)n * CCH * LL + l;
    float xv[16];
#pragma unroll
    for (int c = 0; c < 16; ++c) xv[c] = xp[(size_t)(cs * 16 + c) * LL];

    // partial f48: [0..7]=theta, [8..15]=phi, [16..47]=g
    float f48[48];
#pragma unroll
    for (int k = 0; k < 8; ++k) {
        float a = 0.f;
        const float* w = w_theta + k * 64 + cs * 16;
#pragma unroll
        for (int c = 0; c < 16; ++c) a += w[c] * xv[c];
        f48[k] = a;
    }
#pragma unroll
    for (int k = 0; k < 8; ++k) {
        float a = 0.f;
        const float* w = w_phi + k * 64 + cs * 16;
#pragma unroll
        for (int c = 0; c < 16; ++c) a += w[c] * xv[c];
        f48[8 + k] = a;
    }
#pragma unroll
    for (int j = 0; j < 32; ++j) {
        float a = 0.f;
        const float* w = w_g + j * 64 + cs * 16;
#pragma unroll
        for (int c = 0; c < 16; ++c) a += w[c] * xv[c];
        f48[16 + j] = a;
    }

    // stage partials: lane stride 193 floats == 1 mod 32 -> conflict-free
    {
        float* pp = &part[pix][cs * 48];
#pragma unroll
        for (int f = 0; f < 48; ++f) pp[f] = f48[f];
    }
    __syncthreads();

    // reduce: thread (pix, cs) owns features [cs*12, cs*12+12)
    float fin[12];
#pragma unroll
    for (int j = 0; j < 12; ++j) {
        int f = cs * 12 + j;
        fin[j] = part[pix][f] + part[pix][48 + f] + part[pix][96 + f] + part[pix][144 + f];
    }

    // theta (features 0..7) lives entirely in cs==0 threads -> store direct
    if (cs == 0) {
        float* tout = theta_out + ((size_t)n * LL + l) * 8;
        ((float4*)tout)[0] = make_float4(fin[0], fin[1], fin[2], fin[3]);
        ((float4*)tout)[1] = make_float4(fin[4], fin[5], fin[6], fin[7]);
    }

    // write finals in-place into slot 0 (each thread touches only its own
    // (pix, f-range) -> no cross-thread hazard before the barrier)
#pragma unroll
    for (int j = 0; j < 12; ++j) part[pix][cs * 12 + j] = fin[j];
    __syncthreads();

    // 2x2 maxpool: 16 pooled cols x 40 pooled features (phi 8 + g 32)
    for (int idx = tid; idx < 16 * 40; idx += 256) {
        int pc = idx / 40;
        int f8 = idx - pc * 40;         // 0..7 phi, 8..39 g
        int f  = 8 + f8;
        float v = fmaxf(fmaxf(part[2 * pc][f],      part[2 * pc + 1][f]),
                        fmaxf(part[32 + 2 * pc][f], part[33 + 2 * pc][f]));
        int d = rg * 32 + half * 16 + pc;
        if (f8 < 8) phi_out[((size_t)n * DD + d) * 8 + f8] = v;
        else        g_out[((size_t)n * DD + d) * 32 + (f8 - 8)] = v;
    }
}

// ---------------------------------------------------------------------------
// Kernel 2: fused attention, 4-way D-split. Block = 256 thr = 64 queries x
// 4 d-chunks (one chunk per wave, 256 d each). Grid = N * 64 = 1024 blocks.
// LDS: per-round phi/g slices (40 KB) -> 4 blocks/CU = 16 waves/CU; reused
// as the partial-reduction buffer (stride 133 == 5 mod 32, conflict-free).
// ---------------------------------------------------------------------------
__global__ __launch_bounds__(256) void attn_kernel(
    const float* __restrict__ x,        // [N, 64, 4096]
    const float* __restrict__ theta,    // [N, 4096, 8]
    const float* __restrict__ phi,      // [N, 1024, 8]
    const float* __restrict__ g,        // [N, 1024, 32]
    const float* __restrict__ w_o,      // [64, 32]
    const float* __restrict__ gamma_p,  // scalar
    float* __restrict__ out)            // [N, 64, 4096]
{
    __shared__ __align__(16) char smem[40960];
    float* phi_s = (float*)smem;            // [4][64][8]  = 8 KB
    float* g_s   = (float*)(smem + 8192);   // [4][64][32] = 32 KB
    float* red   = (float*)smem;            // [64][133]   = 34 KB (aliased)

    const int n    = blockIdx.x >> 6;
    const int lblk = blockIdx.x & 63;
    const int tid  = threadIdx.x;
    const int ck   = tid >> 6;              // d-chunk 0..3 (one per wave)
    const int q    = tid & 63;              // query within block
    const int l    = lblk * 64 + q;

    const float4* tsrc = (const float4*)(theta + ((size_t)n * LL + l) * 8);
    float4 t0 = tsrc[0], t1 = tsrc[1];

    float acc[32];
#pragma unroll
    for (int j = 0; j < 32; ++j) acc[j] = 0.f;
    float ssum = 0.f;

    for (int r = 0; r < 4; ++r) {
        __syncthreads();
        const int d0 = ck * 256 + r * 64;   // this wave's 64-d slice
        // wave ck stages its own slice: phi 2 KB + g 8 KB, coalesced float4
        {
            const float4* ps = (const float4*)(phi + ((size_t)n * DD + d0) * 8);
            float4* pd = (float4*)(phi_s + ck * 64 * 8);
            pd[q] = ps[q];
            pd[q + 64] = ps[q + 64];
            const float4* gs = (const float4*)(g + ((size_t)n * DD + d0) * 32);
            float4* gd = (float4*)(g_s + ck * 64 * 32);
#pragma unroll
            for (int i = 0; i < 8; ++i) gd[q + 64 * i] = gs[q + 64 * i];
        }
        __syncthreads();

#pragma unroll 2
        for (int d = 0; d < 64; ++d) {
            const float* pr = phi_s + (ck * 64 + d) * 8;   // wave-uniform -> broadcast
            float4 pa = ((const float4*)pr)[0];
            float4 pb = ((const float4*)pr)[1];
            float s = t0.x * pa.x + t0.y * pa.y + t0.z * pa.z + t0.w * pa.w
                    + t1.x * pb.x + t1.y * pb.y + t1.z * pb.z + t1.w * pb.w;
            float e = __expf(s);
            ssum += e;
            const float4* gp4 = (const float4*)(g_s + (ck * 64 + d) * 32);
#pragma unroll
            for (int j = 0; j < 8; ++j) {
                float4 gv = gp4[j];
                acc[4 * j + 0] += e * gv.x;
                acc[4 * j + 1] += e * gv.y;
                acc[4 * j + 2] += e * gv.z;
                acc[4 * j + 3] += e * gv.w;
            }
        }
    }

    __syncthreads();    // all waves done with staging buffers -> reuse as red
    {
        float* rp = red + q * 133 + ck * 33;   // lane stride 133 -> conflict-free
#pragma unroll
        for (int j = 0; j < 32; ++j) rp[j] = acc[j];
        rp[32] = ssum;
    }
    __syncthreads();

    // epilogue: thread (q, ck) produces output channels [ck*16, ck*16+16)
    float a[32];
    {
        const float* rq = red + q * 133;
#pragma unroll
        for (int j = 0; j < 32; ++j)
            a[j] = rq[j] + rq[33 + j] + rq[66 + j] + rq[99 + j];
        float ss = rq[32] + rq[65] + rq[98] + rq[131];
        float inv = 1.0f / ss;
#pragma unroll
        for (int j = 0; j < 32; ++j) a[j] *= inv;
    }

    const float gamma = gamma_p[0];
    const float* xp = x + (size_t)n * CCH * LL + l;
    float* op = out + (size_t)n * CCH * LL + l;

#pragma unroll 4
    for (int o = 0; o < 16; ++o) {
        const int och = ck * 16 + o;
        const float* wrow = w_o + och * 32;    // wave-uniform, L1-cached
        float v = 0.f;
#pragma unroll
        for (int j = 0; j < 32; ++j) v += wrow[j] * a[j];
        op[(size_t)och * LL] = xp[(size_t)och * LL] + gamma * v;
    }
}

// ---------------------------------------------------------------------------
extern "C" void kernel_launch(void* const* d_in, const int* in_sizes, int n_in,
                              void* d_out, int out_size, void* d_ws, size_t ws_size,
                              hipStream_t stream) {
    const float* x       = (const float*)d_in[0];
    const float* w_theta = (const float*)d_in[1];
    const float* w_phi   = (const float*)d_in[2];
    const float* w_g     = (const float*)d_in[3];
    const float* w_o     = (const float*)d_in[4];
    const float* gamma   = (const float*)d_in[5];
    float* out = (float*)d_out;

    // workspace layout (floats): theta 2 MB | phi 512 KB | g 2 MB
    float* theta_ws = (float*)d_ws;                       // N*L*8  = 524288
    float* phi_ws   = theta_ws + (size_t)NB * LL * 8;     // N*D*8  = 131072
    float* g_ws     = phi_ws   + (size_t)NB * DD * 8;     // N*D*32 = 524288

    prep_kernel<<<1024, 256, 0, stream>>>(x, w_theta, w_phi, w_g,
                                          theta_ws, phi_ws, g_ws);
    attn_kernel<<<1024, 256, 0, stream>>>(x, theta_ws, phi_ws, g_ws,
                                          w_o, gamma, out);
}

// Round 3
// 148.960 us; speedup vs baseline: 1.7878x; 1.4191x over previous
//
#include <hip/hip_runtime.h>
#include <hip/hip_bf16.h>
#include <hip/hip_fp16.h>

#define NB 16
#define CCH 64
#define LL 4096   // 64*64
#define DD 1024   // 32*32

typedef _Float16 h8 __attribute__((ext_vector_type(8)));
typedef _Float16 h2 __attribute__((ext_vector_type(2)));
typedef float    f4v __attribute__((ext_vector_type(4)));

#if defined(__has_builtin)
#if __has_builtin(__builtin_amdgcn_fdot2)
#define HAVE_FDOT2 1
#endif
#if __has_builtin(__builtin_amdgcn_exp2f)
#define EXP2F(x) __builtin_amdgcn_exp2f(x)
#endif
#endif
#ifndef EXP2F
#define EXP2F(x) exp2f(x)
#endif

static __device__ __forceinline__ float fdot2f(h2 a, h2 b, float c) {
#ifdef HAVE_FDOT2
    return __builtin_amdgcn_fdot2(a, b, c, false);
#else
    return c + (float)a[0] * (float)b[0] + (float)a[1] * (float)b[1];
#endif
}

#define MFMA16(a, b, c) __builtin_amdgcn_mfma_f32_16x16x32_f16((a), (b), (c), 0, 0, 0)

// ---------------------------------------------------------------------------
// Kernel 1: 1x1 convs + 2x2 maxpool. Emits f16: theta [N][4096][8] (scaled by
// log2(e)), phi [N][1024][8], gT [N][32][1024] (transposed for MFMA B-frags).
// Block = 256 thr = 64 pixels x 4 channel-quarters; grid = 1024.
// ---------------------------------------------------------------------------
__global__ __launch_bounds__(256) void prep_kernel(
    const float* __restrict__ x,        // [N, 64, 4096]
    const float* __restrict__ w_theta,  // [8, 64]
    const float* __restrict__ w_phi,    // [8, 64]
    const float* __restrict__ w_g,      // [32, 64]
    _Float16* __restrict__ theta_out,   // [N, 4096, 8]  (pre-scaled by log2e)
    _Float16* __restrict__ phi_out,     // [N, 1024, 8]
    _Float16* __restrict__ gT_out)      // [N, 32, 1024]
{
    __shared__ float part[64][193];     // stride 193 == 1 mod 32, conflict-free

    const int n    = blockIdx.x >> 6;
    const int rem  = blockIdx.x & 63;
    const int rg   = rem >> 1;          // row-pair 0..31
    const int half = rem & 1;           // column half
    const int tid  = threadIdx.x;
    const int cs   = tid >> 6;          // channel quarter (wave-uniform)
    const int pix  = tid & 63;
    const int row  = pix >> 5;
    const int col  = pix & 31;
    const int l    = (rg * 2 + row) * 64 + half * 32 + col;

    const float* xp = x + (size_t)n * CCH * LL + l;
    float xv[16];
#pragma unroll
    for (int c = 0; c < 16; ++c) xv[c] = xp[(size_t)(cs * 16 + c) * LL];

    float f48[48];  // [0..7]=theta, [8..15]=phi, [16..47]=g
#pragma unroll
    for (int k = 0; k < 8; ++k) {
        float a = 0.f;
        const float* w = w_theta + k * 64 + cs * 16;
#pragma unroll
        for (int c = 0; c < 16; ++c) a += w[c] * xv[c];
        f48[k] = a;
    }
#pragma unroll
    for (int k = 0; k < 8; ++k) {
        float a = 0.f;
        const float* w = w_phi + k * 64 + cs * 16;
#pragma unroll
        for (int c = 0; c < 16; ++c) a += w[c] * xv[c];
        f48[8 + k] = a;
    }
#pragma unroll
    for (int j = 0; j < 32; ++j) {
        float a = 0.f;
        const float* w = w_g + j * 64 + cs * 16;
#pragma unroll
        for (int c = 0; c < 16; ++c) a += w[c] * xv[c];
        f48[16 + j] = a;
    }

    {
        float* pp = &part[pix][cs * 48];
#pragma unroll
        for (int f = 0; f < 48; ++f) pp[f] = f48[f];
    }
    __syncthreads();

    float fin[12];
#pragma unroll
    for (int j = 0; j < 12; ++j) {
        int f = cs * 12 + j;
        fin[j] = part[pix][f] + part[pix][48 + f] + part[pix][96 + f] + part[pix][144 + f];
    }

    // theta: f16, pre-scaled by log2(e) so attn can use exp2 directly
    if (cs == 0) {
        h8 tv;
#pragma unroll
        for (int k = 0; k < 8; ++k) tv[k] = (_Float16)(fin[k] * 1.44269504f);
        *(h8*)(theta_out + ((size_t)n * LL + l) * 8) = tv;
    }

#pragma unroll
    for (int j = 0; j < 12; ++j) part[pix][cs * 12 + j] = fin[j];
    __syncthreads();

    // 2x2 maxpool -> f16 stores. idx = f*16 + pc (pc fastest => gT coalesced)
    for (int idx = tid; idx < 40 * 16; idx += 256) {
        int f8 = idx >> 4;              // 0..7 phi, 8..39 g
        int pc = idx & 15;
        int f  = 8 + f8;
        float v = fmaxf(fmaxf(part[2 * pc][f],      part[2 * pc + 1][f]),
                        fmaxf(part[32 + 2 * pc][f], part[33 + 2 * pc][f]));
        int d = rg * 32 + half * 16 + pc;
        if (f8 < 8) phi_out[((size_t)n * DD + d) * 8 + f8] = (_Float16)v;
        else        gT_out[((size_t)n * 32 + (f8 - 8)) * DD + d] = (_Float16)v;
    }
}

// ---------------------------------------------------------------------------
// Kernel 2: fused attention via MFMA. Block = 256 thr = 4 waves; each wave
// owns 32 queries (2 M-tiles of 16), full D=1024. Grid = N*32 = 512 blocks.
// K-loop: scores on VALU (v_dot2_f32_f16 + v_exp_f32) packed straight into
// A-frags; g B-frags streamed from global gT (L2-resident); zero barriers.
// Epilogue: normalize (shfl), w_o projection via MFMA, LDS transpose, store.
// ---------------------------------------------------------------------------
__global__ __launch_bounds__(256, 3) void attn_kernel(
    const float*    __restrict__ x,       // [N, 64, 4096]
    const _Float16* __restrict__ theta,   // [N, 4096, 8]
    const _Float16* __restrict__ phi,     // [N, 1024, 8]
    const _Float16* __restrict__ gT,      // [N, 32, 1024]
    const float*    __restrict__ w_o,     // [64, 32]
    const float*    __restrict__ gamma_p, // scalar
    float*          __restrict__ out)     // [N, 64, 4096]
{
    __shared__ float smem[4 * 32 * 36 + 64 * 133];   // 52480 B -> 3 blocks/CU
    float* att_s = smem;                  // per-wave [32][36]
    float* out_s = smem + 4 * 32 * 36;    // [64][133]

    const int n    = blockIdx.x >> 5;
    const int lblk = blockIdx.x & 31;
    const int tid  = threadIdx.x;
    const int w    = tid >> 6;
    const int lane = tid & 63;
    const int m16  = lane & 15;
    const int quad = lane >> 4;
    const int l0   = lblk * 128;          // block query base
    const int qw   = w * 32;              // wave query base within block

    const _Float16* phi_n = phi + (size_t)n * DD * 8;
    const _Float16* gT_n  = gT  + (size_t)n * 32 * DD;

    // theta rows for the wave's two M-tiles (A[m=lane&15][k=quad*8+j])
    h8 th0 = *(const h8*)(theta + ((size_t)n * LL + l0 + qw + m16) * 8);
    h8 th1 = *(const h8*)(theta + ((size_t)n * LL + l0 + qw + 16 + m16) * 8);
    const h2* t0p = (const h2*)&th0;
    const h2* t1p = (const h2*)&th1;

    // w_o B-frags for projection: B[k=gch][n=och], och = m16 + 16v
    h8 wof[4];
#pragma unroll
    for (int v = 0; v < 4; ++v) {
        const float* wr = w_o + (size_t)(m16 + 16 * v) * 32 + quad * 8;
        float4 wa = *(const float4*)wr;
        float4 wb = *(const float4*)(wr + 4);
        wof[v][0] = (_Float16)wa.x; wof[v][1] = (_Float16)wa.y;
        wof[v][2] = (_Float16)wa.z; wof[v][3] = (_Float16)wa.w;
        wof[v][4] = (_Float16)wb.x; wof[v][5] = (_Float16)wb.y;
        wof[v][6] = (_Float16)wb.z; wof[v][7] = (_Float16)wb.w;
    }

    f4v c00 = {0.f, 0.f, 0.f, 0.f}, c01 = c00, c10 = c00, c11 = c00;
    float ssum0 = 0.f, ssum1 = 0.f;

    const _Float16* gr0 = gT_n + (size_t)m16 * DD + quad * 8;        // ch 0..15
    const _Float16* gr1 = gT_n + (size_t)(16 + m16) * DD + quad * 8; // ch 16..31
    const _Float16* pr  = phi_n + (size_t)(quad * 8) * 8;            // phi rows

#pragma unroll 2
    for (int c = 0; c < 32; ++c) {
        const int d0 = c * 32;
        h8 b0 = *(const h8*)(gr0 + d0);   // B[k][ch], k contiguous per lane
        h8 b1 = *(const h8*)(gr1 + d0);
        h8 a0, a1;
#pragma unroll
        for (int j = 0; j < 8; ++j) {
            h8 ph = *(const h8*)(pr + (size_t)(d0 + j) * 8);
            const h2* pp = (const h2*)&ph;
            float s0 = fdot2f(t0p[0], pp[0], 0.f);
            s0 = fdot2f(t0p[1], pp[1], s0);
            s0 = fdot2f(t0p[2], pp[2], s0);
            s0 = fdot2f(t0p[3], pp[3], s0);
            float s1 = fdot2f(t1p[0], pp[0], 0.f);
            s1 = fdot2f(t1p[1], pp[1], s1);
            s1 = fdot2f(t1p[2], pp[2], s1);
            s1 = fdot2f(t1p[3], pp[3], s1);
            float e0 = EXP2F(s0);         // theta pre-scaled by log2e
            float e1 = EXP2F(s1);
            ssum0 += e0; ssum1 += e1;
            a0[j] = (_Float16)e0;
            a1[j] = (_Float16)e1;
        }
        c00 = MFMA16(a0, b0, c00);
        c01 = MFMA16(a0, b1, c01);
        c10 = MFMA16(a1, b0, c10);
        c11 = MFMA16(a1, b1, c11);
    }

    // full softmax denominators: quads hold disjoint d-partials
    ssum0 += __shfl_xor(ssum0, 16); ssum0 += __shfl_xor(ssum0, 32);
    ssum1 += __shfl_xor(ssum1, 16); ssum1 += __shfl_xor(ssum1, 32);
    const float inv0 = 1.0f / ssum0;      // lane holds inv for q = m16 (+16)
    const float inv1 = 1.0f / ssum1;

    // normalize C (row=(lane>>4)*4+reg, col=lane&15) -> att_s[32][36]
    float* as = att_s + w * 32 * 36;
    const int rbase = quad * 4;
#pragma unroll
    for (int r = 0; r < 4; ++r) {
        const int rr = rbase + r;
        const float i0 = __shfl(inv0, rr);
        const float i1 = __shfl(inv1, rr);
        as[rr * 36 + m16]             = c00[r] * i0;
        as[rr * 36 + 16 + m16]        = c01[r] * i0;
        as[(16 + rr) * 36 + m16]      = c10[r] * i1;
        as[(16 + rr) * 36 + 16 + m16] = c11[r] * i1;
    }

    // projection A-frags from att_s (same wave: no barrier needed)
    h8 pa0, pa1;
    {
        const float* r0 = as + m16 * 36 + quad * 8;
        const float* r1 = as + (16 + m16) * 36 + quad * 8;
#pragma unroll
        for (int j = 0; j < 8; ++j) {
            pa0[j] = (_Float16)r0[j];
            pa1[j] = (_Float16)r1[j];
        }
    }

    // out[q][och] = attn_norm[q][:] . w_o[och][:]  via 8 MFMAs
    const f4v zero = {0.f, 0.f, 0.f, 0.f};
#pragma unroll
    for (int v = 0; v < 4; ++v) {
        f4v p0 = MFMA16(pa0, wof[v], zero);
        f4v p1 = MFMA16(pa1, wof[v], zero);
        const int och = m16 + 16 * v;
#pragma unroll
        for (int r = 0; r < 4; ++r) {
            out_s[och * 133 + qw + rbase + r]      = p0[r];
            out_s[och * 133 + qw + 16 + rbase + r] = p1[r];
        }
    }
    __syncthreads();

    // coalesced store + residual: thread -> (och = tid>>2, p = tid&3)
    const float gamma = gamma_p[0];
    const int soch = tid >> 2;
    const int sp   = tid & 3;
    const float* xrow = x   + (size_t)n * CCH * LL + (size_t)soch * LL + l0;
    float*       orow = out + (size_t)n * CCH * LL + (size_t)soch * LL + l0;
    const float* srow = out_s + soch * 133;
#pragma unroll
    for (int i = 0; i < 8; ++i) {
        const int q = i * 16 + sp * 4;
        float4 xv = *(const float4*)(xrow + q);
        float4 ov;
        ov.x = xv.x + gamma * srow[q];
        ov.y = xv.y + gamma * srow[q + 1];
        ov.z = xv.z + gamma * srow[q + 2];
        ov.w = xv.w + gamma * srow[q + 3];
        *(float4*)(orow + q) = ov;
    }
}

// ---------------------------------------------------------------------------
extern "C" void kernel_launch(void* const* d_in, const int* in_sizes, int n_in,
                              void* d_out, int out_size, void* d_ws, size_t ws_size,
                              hipStream_t stream) {
    const float* x       = (const float*)d_in[0];
    const float* w_theta = (const float*)d_in[1];
    const float* w_phi   = (const float*)d_in[2];
    const float* w_g     = (const float*)d_in[3];
    const float* w_o     = (const float*)d_in[4];
    const float* gamma   = (const float*)d_in[5];
    float* out = (float*)d_out;

    // ws layout (f16): theta 1 MB | phi 256 KB | gT 1 MB
    _Float16* theta_h = (_Float16*)d_ws;                    // N*L*8
    _Float16* phi_h   = theta_h + (size_t)NB * LL * 8;      // N*D*8
    _Float16* gT_h    = phi_h   + (size_t)NB * DD * 8;      // N*32*D

    prep_kernel<<<1024, 256, 0, stream>>>(x, w_theta, w_phi, w_g,
                                          theta_h, phi_h, gT_h);
    attn_kernel<<<512, 256, 0, stream>>>(x, theta_h, phi_h, gT_h,
                                         w_o, gamma, out);
}

// Round 4
// 129.318 us; speedup vs baseline: 2.0593x; 1.1519x over previous
//
#include <hip/hip_runtime.h>
#include <hip/hip_bf16.h>
#include <hip/hip_fp16.h>

#define NB 16
#define CCH 64
#define LL 4096   // 64*64
#define DD 1024   // 32*32

typedef _Float16 h8 __attribute__((ext_vector_type(8)));
typedef _Float16 h2 __attribute__((ext_vector_type(2)));
typedef float    f4v __attribute__((ext_vector_type(4)));

#if defined(__has_builtin)
#if __has_builtin(__builtin_amdgcn_fdot2)
#define HAVE_FDOT2 1
#endif
#if __has_builtin(__builtin_amdgcn_exp2f)
#define EXP2F(x) __builtin_amdgcn_exp2f(x)
#endif
#endif
#ifndef EXP2F
#define EXP2F(x) exp2f(x)
#endif

static __device__ __forceinline__ float fdot2f(h2 a, h2 b, float c) {
#ifdef HAVE_FDOT2
    return __builtin_amdgcn_fdot2(a, b, c, false);
#else
    return c + (float)a[0] * (float)b[0] + (float)a[1] * (float)b[1];
#endif
}

#define MFMA16(a, b, c) __builtin_amdgcn_mfma_f32_16x16x32_f16((a), (b), (c), 0, 0, 0)

// ---------------------------------------------------------------------------
// Kernel 1: 1x1 convs + 2x2 maxpool. Emits f16: theta [N][4096][8] (scaled by
// log2(e)), phi [N][1024][8], gT [N][32][1024] (transposed for MFMA B-frags).
// Block = 256 thr = 64 pixels x 4 channel-quarters; grid = 1024.
// ---------------------------------------------------------------------------
__global__ __launch_bounds__(256) void prep_kernel(
    const float* __restrict__ x,        // [N, 64, 4096]
    const float* __restrict__ w_theta,  // [8, 64]
    const float* __restrict__ w_phi,    // [8, 64]
    const float* __restrict__ w_g,      // [32, 64]
    _Float16* __restrict__ theta_out,   // [N, 4096, 8]  (pre-scaled by log2e)
    _Float16* __restrict__ phi_out,     // [N, 1024, 8]
    _Float16* __restrict__ gT_out)      // [N, 32, 1024]
{
    __shared__ float part[64][193];     // stride 193 == 1 mod 32, conflict-free

    const int n    = blockIdx.x >> 6;
    const int rem  = blockIdx.x & 63;
    const int rg   = rem >> 1;          // row-pair 0..31
    const int half = rem & 1;           // column half
    const int tid  = threadIdx.x;
    const int cs   = tid >> 6;          // channel quarter (wave-uniform)
    const int pix  = tid & 63;
    const int row  = pix >> 5;
    const int col  = pix & 31;
    const int l    = (rg * 2 + row) * 64 + half * 32 + col;

    const float* xp = x + (size_t)n * CCH * LL + l;
    float xv[16];
#pragma unroll
    for (int c = 0; c < 16; ++c) xv[c] = xp[(size_t)(cs * 16 + c) * LL];

    float f48[48];  // [0..7]=theta, [8..15]=phi, [16..47]=g
#pragma unroll
    for (int k = 0; k < 8; ++k) {
        float a = 0.f;
        const float* w = w_theta + k * 64 + cs * 16;
#pragma unroll
        for (int c = 0; c < 16; ++c) a += w[c] * xv[c];
        f48[k] = a;
    }
#pragma unroll
    for (int k = 0; k < 8; ++k) {
        float a = 0.f;
        const float* w = w_phi + k * 64 + cs * 16;
#pragma unroll
        for (int c = 0; c < 16; ++c) a += w[c] * xv[c];
        f48[8 + k] = a;
    }
#pragma unroll
    for (int j = 0; j < 32; ++j) {
        float a = 0.f;
        const float* w = w_g + j * 64 + cs * 16;
#pragma unroll
        for (int c = 0; c < 16; ++c) a += w[c] * xv[c];
        f48[16 + j] = a;
    }

    {
        float* pp = &part[pix][cs * 48];
#pragma unroll
        for (int f = 0; f < 48; ++f) pp[f] = f48[f];
    }
    __syncthreads();

    float fin[12];
#pragma unroll
    for (int j = 0; j < 12; ++j) {
        int f = cs * 12 + j;
        fin[j] = part[pix][f] + part[pix][48 + f] + part[pix][96 + f] + part[pix][144 + f];
    }

    // theta: f16, pre-scaled by log2(e) so attn can use exp2 directly
    if (cs == 0) {
        h8 tv;
#pragma unroll
        for (int k = 0; k < 8; ++k) tv[k] = (_Float16)(fin[k] * 1.44269504f);
        *(h8*)(theta_out + ((size_t)n * LL + l) * 8) = tv;
    }

#pragma unroll
    for (int j = 0; j < 12; ++j) part[pix][cs * 12 + j] = fin[j];
    __syncthreads();

    // 2x2 maxpool -> f16 stores. idx = f*16 + pc (pc fastest => gT coalesced)
    for (int idx = tid; idx < 40 * 16; idx += 256) {
        int f8 = idx >> 4;              // 0..7 phi, 8..39 g
        int pc = idx & 15;
        int f  = 8 + f8;
        float v = fmaxf(fmaxf(part[2 * pc][f],      part[2 * pc + 1][f]),
                        fmaxf(part[32 + 2 * pc][f], part[33 + 2 * pc][f]));
        int d = rg * 32 + half * 16 + pc;
        if (f8 < 8) phi_out[((size_t)n * DD + d) * 8 + f8] = (_Float16)v;
        else        gT_out[((size_t)n * 32 + (f8 - 8)) * DD + d] = (_Float16)v;
    }
}

// ---------------------------------------------------------------------------
// Kernel 2: fused attention via MFMA, D-split for occupancy. Block = 256 thr
// = 4 waves = 2 query-groups (32 q) x 2 D-halves (512 d). Grid = N*64 = 1024
// blocks = 4 blocks/CU (LDS 34.6 KB) = 16 waves/CU. phi staged in LDS
// (broadcast-quad reads); g B-frags streamed from global gT (L2-resident);
// zero barriers inside the K-loop. Wave-pairs combine partial C + ssum via
// LDS (stride 33), then each wave projects one 16-q M-tile through w_o MFMAs.
// out_s (stride 67) aliases phi_s (dead after K-loop).
// ---------------------------------------------------------------------------
__global__ __launch_bounds__(256, 4) void attn_kernel(
    const float*    __restrict__ x,       // [N, 64, 4096]
    const _Float16* __restrict__ theta,   // [N, 4096, 8]
    const _Float16* __restrict__ phi,     // [N, 1024, 8]
    const _Float16* __restrict__ gT,      // [N, 32, 1024]
    const float*    __restrict__ w_o,     // [64, 32]
    const float*    __restrict__ gamma_p, // scalar
    float*          __restrict__ out)     // [N, 64, 4096]
{
    // union(phi_s 16384, out_s 64*67*4=17152) + red 2*2*32*33*4=16896 + ssum 512
    __shared__ __align__(16) char smem[17152 + 16896 + 512];
    _Float16* phi_s  = (_Float16*)smem;               // [1024][8] f16
    float*    out_s  = (float*)smem;                  // [64][67]  (aliases phi_s)
    float*    red    = (float*)(smem + 17152);        // [2g][2h][32q][33]
    float*    ssum_s = (float*)(smem + 17152 + 16896);// [2g][2h][32q]

    const int n    = blockIdx.x >> 6;
    const int lblk = blockIdx.x & 63;
    const int tid  = threadIdx.x;
    const int w    = tid >> 6;
    const int g    = w >> 1;              // query group (32 q)
    const int h    = w & 1;               // D half (512 d)
    const int lane = tid & 63;
    const int m16  = lane & 15;
    const int quad = lane >> 4;
    const int l0   = lblk * 64;           // block query base

    const _Float16* gT_n = gT + (size_t)n * 32 * DD;

    // stage full phi[n] (16 KB) into LDS: 1024 float4s, coalesced
    {
        const float4* ps = (const float4*)(phi + (size_t)n * DD * 8);
        float4* pd = (float4*)phi_s;
#pragma unroll
        for (int i = 0; i < 4; ++i) pd[tid + 256 * i] = ps[tid + 256 * i];
    }

    // theta rows for this wave's two M-sub-tiles (A[m=lane&15][k=quad*8+j])
    h8 th0 = *(const h8*)(theta + ((size_t)n * LL + l0 + g * 32 + m16) * 8);
    h8 th1 = *(const h8*)(theta + ((size_t)n * LL + l0 + g * 32 + 16 + m16) * 8);
    const h2* t0p = (const h2*)&th0;
    const h2* t1p = (const h2*)&th1;

    // w_o B-frags: B[k=gch][n=och], och = m16 + 16v
    h8 wof[4];
#pragma unroll
    for (int v = 0; v < 4; ++v) {
        const float* wr = w_o + (size_t)(m16 + 16 * v) * 32 + quad * 8;
        float4 wa = *(const float4*)wr;
        float4 wb = *(const float4*)(wr + 4);
        wof[v][0] = (_Float16)wa.x; wof[v][1] = (_Float16)wa.y;
        wof[v][2] = (_Float16)wa.z; wof[v][3] = (_Float16)wa.w;
        wof[v][4] = (_Float16)wb.x; wof[v][5] = (_Float16)wb.y;
        wof[v][6] = (_Float16)wb.z; wof[v][7] = (_Float16)wb.w;
    }

    __syncthreads();   // phi_s ready

    f4v c00 = {0.f, 0.f, 0.f, 0.f}, c01 = c00, c10 = c00, c11 = c00;
    float ssum0 = 0.f, ssum1 = 0.f;

    const _Float16* gr0 = gT_n + (size_t)m16 * DD + h * 512 + quad * 8;
    const _Float16* gr1 = gT_n + (size_t)(16 + m16) * DD + h * 512 + quad * 8;
    const _Float16* pr  = phi_s + (size_t)(h * 512 + quad * 8) * 8;

#pragma unroll 2
    for (int c = 0; c < 16; ++c) {
        const int d0 = c * 32;
        h8 b0 = *(const h8*)(gr0 + d0);   // B[k][ch], k contiguous per lane
        h8 b1 = *(const h8*)(gr1 + d0);
        h8 a0, a1;
#pragma unroll
        for (int j = 0; j < 8; ++j) {
            h8 ph = *(const h8*)(pr + (size_t)(d0 + j) * 8);  // LDS, quad-broadcast
            const h2* pp = (const h2*)&ph;
            float s0 = fdot2f(t0p[0], pp[0], 0.f);
            s0 = fdot2f(t0p[1], pp[1], s0);
            s0 = fdot2f(t0p[2], pp[2], s0);
            s0 = fdot2f(t0p[3], pp[3], s0);
            float s1 = fdot2f(t1p[0], pp[0], 0.f);
            s1 = fdot2f(t1p[1], pp[1], s1);
            s1 = fdot2f(t1p[2], pp[2], s1);
            s1 = fdot2f(t1p[3], pp[3], s1);
            float e0 = EXP2F(s0);         // theta pre-scaled by log2e
            float e1 = EXP2F(s1);
            ssum0 += e0; ssum1 += e1;
            a0[j] = (_Float16)e0;
            a1[j] = (_Float16)e1;
        }
        c00 = MFMA16(a0, b0, c00);
        c01 = MFMA16(a0, b1, c01);
        c10 = MFMA16(a1, b0, c10);
        c11 = MFMA16(a1, b1, c11);
    }

    // half-D softmax denominators (sum across quads)
    ssum0 += __shfl_xor(ssum0, 16); ssum0 += __shfl_xor(ssum0, 32);
    ssum1 += __shfl_xor(ssum1, 16); ssum1 += __shfl_xor(ssum1, 32);

    // write partial C (C layout: row q = quad*4+r, col ch = m16) and ssum
    {
        float* rg = red + (size_t)(g * 2 + h) * 32 * 33;
#pragma unroll
        for (int r = 0; r < 4; ++r) {
            const int rr = quad * 4 + r;
            rg[rr * 33 + m16]             = c00[r];
            rg[rr * 33 + 16 + m16]        = c01[r];
            rg[(16 + rr) * 33 + m16]      = c10[r];
            rg[(16 + rr) * 33 + 16 + m16] = c11[r];
        }
        if (quad == 0) {
            ssum_s[(g * 2 + h) * 32 + m16]      = ssum0;
            ssum_s[(g * 2 + h) * 32 + 16 + m16] = ssum1;
        }
    }
    __syncthreads();   // red complete; phi_s dead -> out_s region reusable

    // combine halves + normalize + pack A-frag. Wave (g,h) owns M-tile t=h of
    // group g: queries qloc = g*32 + h*16 + m16, k = gch = quad*8+j.
    h8 pa;
    {
        const float* r0 = red + (size_t)(g * 2 + 0) * 32 * 33 + (h * 16 + m16) * 33 + quad * 8;
        const float* r1 = red + (size_t)(g * 2 + 1) * 32 * 33 + (h * 16 + m16) * 33 + quad * 8;
        float ss = ssum_s[(g * 2) * 32 + h * 16 + m16]
                 + ssum_s[(g * 2 + 1) * 32 + h * 16 + m16];
        float inv = 1.0f / ss;
#pragma unroll
        for (int j = 0; j < 8; ++j) pa[j] = (_Float16)((r0[j] + r1[j]) * inv);
    }

    // projection: out[q][och] via 4 MFMAs (D row q = quad*4+r, col och = m16+16v)
    const f4v zero = {0.f, 0.f, 0.f, 0.f};
#pragma unroll
    for (int v = 0; v < 4; ++v) {
        f4v p = MFMA16(pa, wof[v], zero);
        const int och = m16 + 16 * v;
        float* od = out_s + (size_t)och * 67 + g * 32 + h * 16 + quad * 4;
#pragma unroll
        for (int r = 0; r < 4; ++r) od[r] = p[r];
    }
    __syncthreads();

    // coalesced store + residual: thread -> (och = tid>>2, 16 q starting sp*16)
    const float gamma = gamma_p[0];
    const int soch = tid >> 2;
    const int sp   = tid & 3;
    const float* xrow = x   + (size_t)n * CCH * LL + (size_t)soch * LL + l0;
    float*       orow = out + (size_t)n * CCH * LL + (size_t)soch * LL + l0;
    const float* srow = out_s + (size_t)soch * 67;
#pragma unroll
    for (int i = 0; i < 4; ++i) {
        const int q = sp * 16 + i * 4;
        float4 xv = *(const float4*)(xrow + q);
        float4 ov;
        ov.x = xv.x + gamma * srow[q];
        ov.y = xv.y + gamma * srow[q + 1];
        ov.z = xv.z + gamma * srow[q + 2];
        ov.w = xv.w + gamma * srow[q + 3];
        *(float4*)(orow + q) = ov;
    }
}

// ---------------------------------------------------------------------------
extern "C" void kernel_launch(void* const* d_in, const int* in_sizes, int n_in,
                              void* d_out, int out_size, void* d_ws, size_t ws_size,
                              hipStream_t stream) {
    const float* x       = (const float*)d_in[0];
    const float* w_theta = (const float*)d_in[1];
    const float* w_phi   = (const float*)d_in[2];
    const float* w_g     = (const float*)d_in[3];
    const float* w_o     = (const float*)d_in[4];
    const float* gamma   = (const float*)d_in[5];
    float* out = (float*)d_out;

    // ws layout (f16): theta 1 MB | phi 256 KB | gT 1 MB
    _Float16* theta_h = (_Float16*)d_ws;                    // N*L*8
    _Float16* phi_h   = theta_h + (size_t)NB * LL * 8;      // N*D*8
    _Float16* gT_h    = phi_h   + (size_t)NB * DD * 8;      // N*32*D

    prep_kernel<<<1024, 256, 0, stream>>>(x, w_theta, w_phi, w_g,
                                          theta_h, phi_h, gT_h);
    attn_kernel<<<1024, 256, 0, stream>>>(x, theta_h, phi_h, gT_h,
                                          w_o, gamma, out);
}